// Round 4
// baseline (43.257 us; speedup 1.0000x reference)
//
#include <hip/hip_runtime.h>

#define KMAX 64
#define BB 4
#define LL 4096
#define DD 64
#define TOK (BB * LL)        // 16384 tokens per side
#define SLOTS 8192           // hash-table slots per batch (load factor 0.5)
#define EMPTY 0xFFFFFFFFFFFFFFFFull

typedef unsigned long long u64;

__device__ __forceinline__ int hash_code(int code) {
    return (int)(((unsigned)code * 2654435761u) >> 19) & (SLOTS - 1); // 13 bits
}

// Table init: 256 KB of 0xFF. hipMemsetAsync's fillBuffer took ~40us in-graph
// (measured R3) -> do it ourselves: 16384 threads x one int4 store.
__global__ __launch_bounds__(256) void init_table_kernel(int4* __restrict__ table) {
    int t = blockIdx.x * 256 + threadIdx.x;
    table[t] = make_int4(-1, -1, -1, -1);
}

// Phase 1: one thread per token-side. Query threads store their code; key
// threads CAS-insert (code<<12 | j) into the per-batch hash table.
// Float accumulation order d=0..63 is bitwise-verified (absmax 0.0) — DO NOT
// change to a tree reduction.
__global__ __launch_bounds__(64) void codes_build_kernel(
        const float* __restrict__ q,
        const float* __restrict__ k,
        const float* __restrict__ W,
        int* __restrict__ qcodes,
        u64* __restrict__ table /* [BB][SLOTS], pre-initialized to 0xFF */) {
    __shared__ float sW[DD * 4];
    int lane = threadIdx.x;   // block = 64 = one wave
    #pragma unroll
    for (int i = 0; i < 4; ++i) sW[i * 64 + lane] = W[i * 64 + lane];
    __syncthreads();

    int u = blockIdx.x * 64 + lane;          // grid covers 2*TOK exactly
    const float* src = (u < TOK) ? q : k;
    int t = u & (TOK - 1);

    const float4* xp = (const float4*)(src + (size_t)t * DD);
    float4 x[16];
    #pragma unroll
    for (int i = 0; i < 16; ++i) x[i] = xp[i];

    float p0 = 0.f, p1 = 0.f, p2 = 0.f, p3 = 0.f;
    const float4* wrow = (const float4*)sW;
    #pragma unroll
    for (int d = 0; d < DD; ++d) {
        float xv = ((const float*)x)[d];
        float b = (xv > 0.f) ? 1.0f : 0.0f;      // binary_quantize
        float4 w = wrow[d];
        p0 = fmaf(b, w.x, p0);
        p1 = fmaf(b, w.y, p1);
        p2 = fmaf(b, w.z, p2);
        p3 = fmaf(b, w.w, p3);
    }
    int h0 = ((int)floorf(p0 * 0.5f)) & 31;      // floor(p/2) mod 32
    int h1 = ((int)floorf(p1 * 0.5f)) & 31;
    int h2 = ((int)floorf(p2 * 0.5f)) & 31;
    int h3 = ((int)floorf(p3 * 0.5f)) & 31;
    int code = h0 | (h1 << 5) | (h2 << 10) | (h3 << 15);   // < 2^20

    if (u < TOK) {
        qcodes[u] = code;
    } else {
        int b = t >> 12;                 // batch
        int j = t & (LL - 1);            // key index, 12 bits
        u64 entry = ((u64)(unsigned)code << 12) | (unsigned)j;
        u64* tb = table + (size_t)b * SLOTS;
        int h = hash_code(code);
        for (int step = 0; step < SLOTS; ++step) {
            u64 prev = atomicCAS(&tb[h], EMPTY, entry);
            if (prev == EMPTY) break;    // claimed
            h = (h + 1) & (SLOTS - 1);
        }
    }
}

// Phase 2: one THREAD per query. Probe the table from h(code) until the
// first empty slot; linear-probing invariant guarantees every entry with
// this code lies on that path. Keep the 64 smallest j ascending (capped
// insertion sort in LDS), pad with -1, write as int4.
__global__ __launch_bounds__(64) void query_kernel(
        const int* __restrict__ qcodes,
        const u64* __restrict__ table,
        int* __restrict__ out) {
    __shared__ int cand[64 * 65];        // stride 65 -> bank-conflict-free
    int tid = threadIdx.x;
    int t = blockIdx.x * 64 + tid;       // query id, grid covers TOK exactly
    int b = t >> 12;
    int code = qcodes[t];
    const u64* tb = table + (size_t)b * SLOTS;
    u64 want = (u64)(unsigned)code;
    int* my = cand + tid * 65;
    int cnt = 0;

    int h = hash_code(code);
    for (int step = 0; step < SLOTS; ++step) {
        u64 e = tb[h];
        if (e == EMPTY) break;
        if ((e >> 12) == want) {
            int j = (int)(e & 0xFFF);
            if (cnt < KMAX) {
                int p = cnt++;
                while (p > 0 && my[p - 1] > j) { my[p] = my[p - 1]; --p; }
                my[p] = j;
            } else if (j < my[KMAX - 1]) {
                int p = KMAX - 1;
                while (p > 0 && my[p - 1] > j) { my[p] = my[p - 1]; --p; }
                my[p] = j;
            }
        }
        h = (h + 1) & (SLOTS - 1);
    }
    for (int i = cnt; i < KMAX; ++i) my[i] = -1;

    int4* op = (int4*)(out + (size_t)t * KMAX);
    #pragma unroll
    for (int i = 0; i < 16; ++i)
        op[i] = make_int4(my[4 * i], my[4 * i + 1], my[4 * i + 2], my[4 * i + 3]);
}

extern "C" void kernel_launch(void* const* d_in, const int* in_sizes, int n_in,
                              void* d_out, int out_size, void* d_ws, size_t ws_size,
                              hipStream_t stream) {
    const float* q = (const float*)d_in[0];
    const float* k = (const float*)d_in[1];
    const float* W = (const float*)d_in[2];
    int* out = (int*)d_out;

    int* qcodes = (int*)d_ws;                                  // 16384 ints (64 KB)
    u64* table = (u64*)((char*)d_ws + 65536);                  // 4*8192 u64 (256 KB)

    // 32768 u64 = 16384 int4 stores
    init_table_kernel<<<16384 / 256, 256, 0, stream>>>((int4*)table);

    codes_build_kernel<<<(2 * TOK) / 64, 64, 0, stream>>>(q, k, W, qcodes, table);
    query_kernel<<<TOK / 64, 64, 0, stream>>>(qcodes, table, out);
}

// Round 5
// 31.494 us; speedup vs baseline: 1.3735x; 1.3735x over previous
//
#include <hip/hip_runtime.h>

#define KMAX 64
#define BB 4
#define LL 4096
#define DD 64
#define TOK (BB * LL)   // 16384 tokens per side
#define QPW 8           // queries per wave
#define WPB 4           // waves per block
#define QPB (QPW * WPB) // 32 queries per block
#define BLKS_PER_BATCH (LL / QPB)   // 128

// Phase 1 (verbatim from R2, bitwise-verified absmax 0.0): one thread per
// token-side. Accumulation strictly sequential d=0..63 — DO NOT change to a
// tree reduction (floor() at bucket edges is order-sensitive).
__global__ __launch_bounds__(64) void codes_kernel(
        const float* __restrict__ q,
        const float* __restrict__ k,
        const float* __restrict__ W,
        int* __restrict__ codes /* [0,TOK)=qcodes, [TOK,2*TOK)=kcodes */) {
    __shared__ float sW[DD * 4];
    int lane = threadIdx.x;   // block = 64 = one wave
    #pragma unroll
    for (int i = 0; i < 4; ++i) sW[i * 64 + lane] = W[i * 64 + lane];
    __syncthreads();

    int u = blockIdx.x * 64 + lane;          // grid covers 2*TOK exactly
    const float* src = (u < TOK) ? q : k;
    int t = u & (TOK - 1);

    const float4* xp = (const float4*)(src + (size_t)t * DD);
    float4 x[16];
    #pragma unroll
    for (int i = 0; i < 16; ++i) x[i] = xp[i];

    float p0 = 0.f, p1 = 0.f, p2 = 0.f, p3 = 0.f;
    const float4* wrow = (const float4*)sW;
    #pragma unroll
    for (int d = 0; d < DD; ++d) {
        float xv = ((const float*)x)[d];
        float b = (xv > 0.f) ? 1.0f : 0.0f;      // binary_quantize
        float4 w = wrow[d];
        p0 = fmaf(b, w.x, p0);
        p1 = fmaf(b, w.y, p1);
        p2 = fmaf(b, w.z, p2);
        p3 = fmaf(b, w.w, p3);
    }
    int h0 = ((int)floorf(p0 * 0.5f)) & 31;      // floor(p/2) mod 32
    int h1 = ((int)floorf(p1 * 0.5f)) & 31;
    int h2 = ((int)floorf(p2 * 0.5f)) & 31;
    int h3 = ((int)floorf(p3 * 0.5f)) & 31;
    codes[u] = h0 | (h1 << 5) | (h2 << 10) | (h3 << 15);
}

// Phase 2: block stages its batch's 4096 k-codes in LDS (16 KB), then each
// wave scans chunks c=0..63 once, comparing against 8 queries per chunk.
// Per query the ballot/popc ordered-write logic is identical to the
// R1/R2-verified version: count accumulates in increasing-j order, matched
// lanes write at count + popc(lower-lane mask), pos<KMAX guard, -1 tail.
__global__ __launch_bounds__(256) void find_kernel(
        const int* __restrict__ qcodes,
        const int* __restrict__ kcodes,
        int* __restrict__ out) {
    __shared__ int skc[LL];              // 16 KB
    int tid = threadIdx.x;
    int blk = blockIdx.x;                // 512 blocks total
    int b = blk >> 7;                    // blk / BLKS_PER_BATCH

    // stage k-codes for this batch (int4 = 16B per thread-load)
    const int4* src = (const int4*)(kcodes + b * LL);
    int4* dst = (int4*)skc;
    #pragma unroll
    for (int i = 0; i < LL / 4 / 256; ++i)       // 4 iters
        dst[tid + i * 256] = src[tid + i * 256];
    __syncthreads();

    int wave = tid >> 6, lane = tid & 63;
    int qbase = (blk & (BLKS_PER_BATCH - 1)) * QPB + wave * QPW;  // within batch
    const int* qp = qcodes + b * LL + qbase;
    int qcv[QPW];
    #pragma unroll
    for (int i = 0; i < QPW; ++i) qcv[i] = qp[i];

    unsigned long long lowmask = (1ull << lane) - 1ull;
    int cnt[QPW];
    #pragma unroll
    for (int i = 0; i < QPW; ++i) cnt[i] = 0;
    int* outb = out + (size_t)(b * LL + qbase) * KMAX;

    for (int c = 0; c < LL / 64; ++c) {          // 64 chunks
        int kv = skc[c * 64 + lane];             // stride-4B: conflict-free
        int j = c * 64 + lane;
        #pragma unroll
        for (int i = 0; i < QPW; ++i) {
            bool m = (kv == qcv[i]);
            unsigned long long bal = __ballot(m);
            if (m) {
                int pos = cnt[i] + __popcll(bal & lowmask);
                if (pos < KMAX) outb[(size_t)i * KMAX + pos] = j;
            }
            cnt[i] += __popcll(bal);
        }
    }
    // tail fill with -1 (coalesced: 64 consecutive ints per query)
    #pragma unroll
    for (int i = 0; i < QPW; ++i) {
        int p = cnt[i] + lane;
        if (p < KMAX) outb[(size_t)i * KMAX + p] = -1;
    }
}

extern "C" void kernel_launch(void* const* d_in, const int* in_sizes, int n_in,
                              void* d_out, int out_size, void* d_ws, size_t ws_size,
                              hipStream_t stream) {
    const float* q = (const float*)d_in[0];
    const float* k = (const float*)d_in[1];
    const float* W = (const float*)d_in[2];
    int* out = (int*)d_out;
    int* codes = (int*)d_ws;                 // [2*TOK] ints (128 KB)
    int* qcodes = codes;
    int* kcodes = codes + TOK;

    codes_kernel<<<(2 * TOK) / 64, 64, 0, stream>>>(q, k, W, codes);

    find_kernel<<<TOK / QPB, 256, 0, stream>>>(qcodes, kcodes, out);
}

// Round 6
// 26.750 us; speedup vs baseline: 1.6171x; 1.1774x over previous
//
#include <hip/hip_runtime.h>

#define KMAX 64
#define BB 4
#define LL 4096
#define DD 64
#define TOK (BB * LL)   // 16384 tokens per side
#define QPW 8           // queries per wave
#define WPB 4           // waves per block
#define QPB (QPW * WPB) // 32 queries per block
#define BLKS_PER_BATCH (LL / QPB)   // 128

typedef unsigned long long u64;

// Phase 1 (verbatim, bitwise-verified absmax 0.0): one thread per token-side.
// Accumulation strictly sequential d=0..63 — DO NOT change to a tree
// reduction (floor() at bucket edges is order-sensitive).
__global__ __launch_bounds__(64) void codes_kernel(
        const float* __restrict__ q,
        const float* __restrict__ k,
        const float* __restrict__ W,
        int* __restrict__ codes /* [0,TOK)=qcodes, [TOK,2*TOK)=kcodes */) {
    __shared__ float sW[DD * 4];
    int lane = threadIdx.x;   // block = 64 = one wave
    #pragma unroll
    for (int i = 0; i < 4; ++i) sW[i * 64 + lane] = W[i * 64 + lane];
    __syncthreads();

    int u = blockIdx.x * 64 + lane;          // grid covers 2*TOK exactly
    const float* src = (u < TOK) ? q : k;
    int t = u & (TOK - 1);

    const float4* xp = (const float4*)(src + (size_t)t * DD);
    float4 x[16];
    #pragma unroll
    for (int i = 0; i < 16; ++i) x[i] = xp[i];

    float p0 = 0.f, p1 = 0.f, p2 = 0.f, p3 = 0.f;
    const float4* wrow = (const float4*)sW;
    #pragma unroll
    for (int d = 0; d < DD; ++d) {
        float xv = ((const float*)x)[d];
        float b = (xv > 0.f) ? 1.0f : 0.0f;      // binary_quantize
        float4 w = wrow[d];
        p0 = fmaf(b, w.x, p0);
        p1 = fmaf(b, w.y, p1);
        p2 = fmaf(b, w.z, p2);
        p3 = fmaf(b, w.w, p3);
    }
    int h0 = ((int)floorf(p0 * 0.5f)) & 31;      // floor(p/2) mod 32
    int h1 = ((int)floorf(p1 * 0.5f)) & 31;
    int h2 = ((int)floorf(p2 * 0.5f)) & 31;
    int h3 = ((int)floorf(p3 * 0.5f)) & 31;
    codes[u] = h0 | (h1 << 5) | (h2 << 10) | (h3 << 15);
}

__device__ __forceinline__ unsigned bloom_h(int code) {
    return ((unsigned)code * 2654435761u) >> 17;   // 15 bits
}

// Phase 2: stage batch k-codes (16 KB) + build a 32768-bit Bloom filter of
// key codes (4 KB) in LDS. Per query (wave-uniform code): one bloom bit test
// -> ~85% of queries write 64 x -1 and skip the scan. Needed queries scan 16
// groups of 256 j via ds_read_b128; groups with ballot==0 (the usual case)
// cost ~a cmp+branch. Match path preserves exact increasing-j order:
// j = g*256 + lane*4 + e is lane-major, 'before' counts all matches in lower
// lanes (4 ballots & lowmask), within-lane order by sequential pos++.
__global__ __launch_bounds__(256) void find_kernel(
        const int* __restrict__ qcodes,
        const int* __restrict__ kcodes,
        int* __restrict__ out) {
    __shared__ int skc[LL];              // 16 KB
    __shared__ unsigned sbloom[1024];    // 4 KB = 32768 bits
    int tid = threadIdx.x;
    int blk = blockIdx.x;                // 512 blocks
    int b = blk >> 7;                    // batch

    const int4* src = (const int4*)(kcodes + b * LL);
    int4* dst = (int4*)skc;
    #pragma unroll
    for (int i = 0; i < 4; ++i) dst[tid + i * 256] = src[tid + i * 256];
    #pragma unroll
    for (int i = 0; i < 4; ++i) sbloom[tid + i * 256] = 0u;
    __syncthreads();
    #pragma unroll
    for (int i = 0; i < 16; ++i) {
        unsigned h = bloom_h(skc[tid + i * 256]);   // stride-1: conflict-free
        atomicOr(&sbloom[h >> 5], 1u << (h & 31));
    }
    __syncthreads();

    int wave = tid >> 6, lane = tid & 63;
    int qbase = (blk & (BLKS_PER_BATCH - 1)) * QPB + wave * QPW;
    const int* qp = qcodes + b * LL + qbase;
    int* outb = out + (size_t)(b * LL + qbase) * KMAX;
    u64 lowmask = (1ull << lane) - 1ull;
    const int4* skc4 = (const int4*)skc;

    for (int i = 0; i < QPW; ++i) {
        int qc = qp[i];
        int* op = outb + i * KMAX;
        unsigned h = bloom_h(qc);
        if (!((sbloom[h >> 5] >> (h & 31)) & 1u)) {  // wave-uniform test
            op[lane] = -1;                           // 64 lanes cover 64 slots
            continue;
        }
        int count = 0;
        for (int g = 0; g < 16; ++g) {               // 256 j per group
            int4 kv = skc4[g * 64 + lane];
            bool m0 = (kv.x == qc), m1 = (kv.y == qc);
            bool m2 = (kv.z == qc), m3 = (kv.w == qc);
            if (__ballot(m0 | m1 | m2 | m3) == 0) continue;  // usual case
            u64 b0 = __ballot(m0), b1 = __ballot(m1);
            u64 b2 = __ballot(m2), b3 = __ballot(m3);
            int before = __popcll(b0 & lowmask) + __popcll(b1 & lowmask)
                       + __popcll(b2 & lowmask) + __popcll(b3 & lowmask);
            int pos = count + before;
            int j0 = g * 256 + lane * 4;
            if (m0) { if (pos < KMAX) op[pos] = j0;     ++pos; }
            if (m1) { if (pos < KMAX) op[pos] = j0 + 1; ++pos; }
            if (m2) { if (pos < KMAX) op[pos] = j0 + 2; ++pos; }
            if (m3) { if (pos < KMAX) op[pos] = j0 + 3; ++pos; }
            count += __popcll(b0) + __popcll(b1) + __popcll(b2) + __popcll(b3);
        }
        int p = count + lane;
        if (p < KMAX) op[p] = -1;
    }
}

extern "C" void kernel_launch(void* const* d_in, const int* in_sizes, int n_in,
                              void* d_out, int out_size, void* d_ws, size_t ws_size,
                              hipStream_t stream) {
    const float* q = (const float*)d_in[0];
    const float* k = (const float*)d_in[1];
    const float* W = (const float*)d_in[2];
    int* out = (int*)d_out;
    int* codes = (int*)d_ws;                 // [2*TOK] ints (128 KB)
    int* qcodes = codes;
    int* kcodes = codes + TOK;

    codes_kernel<<<(2 * TOK) / 64, 64, 0, stream>>>(q, k, W, codes);

    find_kernel<<<TOK / QPB, 256, 0, stream>>>(qcodes, kcodes, out);
}

// Round 7
// 23.690 us; speedup vs baseline: 1.8260x; 1.1292x over previous
//
#include <hip/hip_runtime.h>

#define KMAX 64
#define BB 4
#define LL 4096
#define DD 64
#define TOK (BB * LL)   // 16384 tokens per side

typedef unsigned long long u64;

// Phase 1 (verbatim, bitwise-verified absmax 0.0 since R1): one thread per
// token-side. Accumulation strictly sequential d=0..63 — DO NOT change to a
// tree reduction (floor() at bucket edges is order-sensitive).
__global__ __launch_bounds__(64) void codes_kernel(
        const float* __restrict__ q,
        const float* __restrict__ k,
        const float* __restrict__ W,
        int* __restrict__ codes /* [0,TOK)=qcodes, [TOK,2*TOK)=kcodes */) {
    __shared__ float sW[DD * 4];
    int lane = threadIdx.x;   // block = 64 = one wave
    #pragma unroll
    for (int i = 0; i < 4; ++i) sW[i * 64 + lane] = W[i * 64 + lane];
    __syncthreads();

    int u = blockIdx.x * 64 + lane;          // grid covers 2*TOK exactly
    const float* src = (u < TOK) ? q : k;
    int t = u & (TOK - 1);

    const float4* xp = (const float4*)(src + (size_t)t * DD);
    float4 x[16];
    #pragma unroll
    for (int i = 0; i < 16; ++i) x[i] = xp[i];

    float p0 = 0.f, p1 = 0.f, p2 = 0.f, p3 = 0.f;
    const float4* wrow = (const float4*)sW;
    #pragma unroll
    for (int d = 0; d < DD; ++d) {
        float xv = ((const float*)x)[d];
        float b = (xv > 0.f) ? 1.0f : 0.0f;      // binary_quantize
        float4 w = wrow[d];
        p0 = fmaf(b, w.x, p0);
        p1 = fmaf(b, w.y, p1);
        p2 = fmaf(b, w.z, p2);
        p3 = fmaf(b, w.w, p3);
    }
    int h0 = ((int)floorf(p0 * 0.5f)) & 31;      // floor(p/2) mod 32
    int h1 = ((int)floorf(p1 * 0.5f)) & 31;
    int h2 = ((int)floorf(p2 * 0.5f)) & 31;
    int h3 = ((int)floorf(p3 * 0.5f)) & 31;
    codes[u] = h0 | (h1 << 5) | (h2 << 10) | (h3 << 15);
}

// Phase 2: ONE WAVE PER QUERY (16384 waves -> 16 waves/SIMD latency hiding,
// the R5 lesson) x 4-wide int4 groups (the R6 lesson: 16 iterations, not 64).
// kcodes/batch = 16 KB -> L1-resident after first touch; no LDS, no barrier.
// Group-match block is verbatim from R6 (absmax 0.0): lane-major
// j = g*256 + lane*4 + e; 'before' = sum of 4 ballots & lowmask (all matches
// in lower lanes); within-lane order via sequential pos++. Early-exit when
// count >= KMAX (count only grows; pos>=count>=KMAX can't write).
__global__ __launch_bounds__(256) void find_kernel(
        const int* __restrict__ qcodes,
        const int* __restrict__ kcodes,
        int* __restrict__ out) {
    int gtid = blockIdx.x * 256 + threadIdx.x;
    int wave = gtid >> 6;                // query id, grid covers TOK exactly
    int lane = gtid & 63;
    int b = wave >> 12;
    int qc = qcodes[wave];               // wave-uniform broadcast load
    const int4* kc4 = (const int4*)(kcodes + b * LL);
    int* op = out + (size_t)wave * KMAX;
    u64 lowmask = (1ull << lane) - 1ull;

    int count = 0;
    for (int g = 0; g < LL / 256 && count < KMAX; ++g) {   // 16 groups
        int4 kv = kc4[g * 64 + lane];
        bool m0 = (kv.x == qc), m1 = (kv.y == qc);
        bool m2 = (kv.z == qc), m3 = (kv.w == qc);
        if (__ballot(m0 | m1 | m2 | m3) == 0) continue;    // usual case
        u64 b0 = __ballot(m0), b1 = __ballot(m1);
        u64 b2 = __ballot(m2), b3 = __ballot(m3);
        int before = __popcll(b0 & lowmask) + __popcll(b1 & lowmask)
                   + __popcll(b2 & lowmask) + __popcll(b3 & lowmask);
        int pos = count + before;
        int j0 = g * 256 + lane * 4;
        if (m0) { if (pos < KMAX) op[pos] = j0;     ++pos; }
        if (m1) { if (pos < KMAX) op[pos] = j0 + 1; ++pos; }
        if (m2) { if (pos < KMAX) op[pos] = j0 + 2; ++pos; }
        if (m3) { if (pos < KMAX) op[pos] = j0 + 3; ++pos; }
        count += __popcll(b0) + __popcll(b1) + __popcll(b2) + __popcll(b3);
    }
    int p = count + lane;
    if (p < KMAX) op[p] = -1;            // coalesced tail fill
}

extern "C" void kernel_launch(void* const* d_in, const int* in_sizes, int n_in,
                              void* d_out, int out_size, void* d_ws, size_t ws_size,
                              hipStream_t stream) {
    const float* q = (const float*)d_in[0];
    const float* k = (const float*)d_in[1];
    const float* W = (const float*)d_in[2];
    int* out = (int*)d_out;
    int* codes = (int*)d_ws;                 // [2*TOK] ints (128 KB)
    int* qcodes = codes;
    int* kcodes = codes + TOK;

    codes_kernel<<<(2 * TOK) / 64, 64, 0, stream>>>(q, k, W, codes);

    const int total_threads = TOK * 64;      // one wave per query
    find_kernel<<<total_threads / 256, 256, 0, stream>>>(qcodes, kcodes, out);
}